// Round 1
// baseline (1377.070 us; speedup 1.0000x reference)
//
#include <hip/hip_runtime.h>

#define HDIM 32
#define IN_DIM 128
#define NEG_SLOPE 0.2f

// Layer-1 GEMM: h = x @ W (N x 128 @ 128 x 32), es = h @ a_s, ed = h @ a_d
__global__ __launch_bounds__(256) void gemm128(
    const float* __restrict__ x, const float* __restrict__ W,
    const float* __restrict__ a_s, const float* __restrict__ a_d,
    float* __restrict__ h, float* __restrict__ es, float* __restrict__ ed, int N)
{
    __shared__ float Ws[IN_DIM * HDIM];   // 16 KB
    __shared__ float xs[8][IN_DIM];       // 4 KB
    const int tid = threadIdx.x;
    for (int i = tid; i < IN_DIM * HDIM; i += 256) Ws[i] = W[i];
    const int col = tid & 31;
    const int rl  = tid >> 5;
    const float as_c = a_s[col], ad_c = a_d[col];
    for (int tile = blockIdx.x; tile * 8 < N; tile += gridDim.x) {
        const int row0 = tile * 8;
        __syncthreads();
        for (int i = tid; i < 8 * IN_DIM; i += 256) {
            int r = i >> 7, c = i & 127;
            int gr = row0 + r;
            xs[r][c] = (gr < N) ? x[(size_t)gr * IN_DIM + c] : 0.f;
        }
        __syncthreads();
        const int row = row0 + rl;
        float acc = 0.f;
        #pragma unroll 8
        for (int k = 0; k < IN_DIM; k++) acc += xs[rl][k] * Ws[k * HDIM + col];
        float ps = acc * as_c, pd = acc * ad_c;
        #pragma unroll
        for (int m = 16; m >= 1; m >>= 1) { ps += __shfl_xor(ps, m); pd += __shfl_xor(pd, m); }
        if (row < N) {
            h[(size_t)row * HDIM + col] = acc;
            if (col == 0) { es[row] = ps; ed[row] = pd; }
        }
    }
}

// Layers 2-4 GEMM: h = x @ W (N x 32 @ 32 x 32), plus es/ed
__global__ __launch_bounds__(256) void gemm32(
    const float* __restrict__ x, const float* __restrict__ W,
    const float* __restrict__ a_s, const float* __restrict__ a_d,
    float* __restrict__ h, float* __restrict__ es, float* __restrict__ ed, int N)
{
    __shared__ float Ws[HDIM * HDIM];     // 4 KB
    __shared__ float xs[8][HDIM];         // 1 KB
    const int tid = threadIdx.x;
    for (int i = tid; i < HDIM * HDIM; i += 256) Ws[i] = W[i];
    const int col = tid & 31;
    const int rl  = tid >> 5;
    const float as_c = a_s[col], ad_c = a_d[col];
    for (int tile = blockIdx.x; tile * 8 < N; tile += gridDim.x) {
        const int row0 = tile * 8;
        __syncthreads();
        {
            int i = tid;                  // 256 threads load exactly 8*32
            int r = i >> 5, c = i & 31;
            int gr = row0 + r;
            xs[r][c] = (gr < N) ? x[(size_t)gr * HDIM + c] : 0.f;
        }
        __syncthreads();
        const int row = row0 + rl;
        float acc = 0.f;
        #pragma unroll
        for (int k = 0; k < HDIM; k++) acc += xs[rl][k] * Ws[k * HDIM + col];
        float ps = acc * as_c, pd = acc * ad_c;
        #pragma unroll
        for (int m = 16; m >= 1; m >>= 1) { ps += __shfl_xor(ps, m); pd += __shfl_xor(pd, m); }
        if (row < N) {
            h[(size_t)row * HDIM + col] = acc;
            if (col == 0) { es[row] = ps; ed[row] = pd; }
        }
    }
}

// One 32-lane group per edge: w = exp(leaky_relu(es[src]+ed[dst]));
// acc[dst][:] += w*h[src][:]; denom[dst] += w.
__global__ __launch_bounds__(256) void edge_kernel(
    const float* __restrict__ h, const float* __restrict__ es, const float* __restrict__ ed,
    const int* __restrict__ srcs, const int* __restrict__ dsts, int E, int Etot,
    float* __restrict__ acc, float* __restrict__ denom)
{
    int t = blockIdx.x * blockDim.x + threadIdx.x;
    int lane = t & 31;
    int eidx = t >> 5;
    if (eidx >= Etot) return;
    int s, d;
    if (eidx < E) { s = srcs[eidx]; d = dsts[eidx]; }
    else          { s = d = eidx - E; }
    float e = es[s] + ed[d];
    e = (e >= 0.f) ? e : NEG_SLOPE * e;
    float w = __expf(e);
    atomicAdd(&acc[(size_t)d * HDIM + lane], w * h[(size_t)s * HDIM + lane]);
    if (lane == 0) atomicAdd(&denom[d], w);
}

// acc[i][f] = acc[i][f]/denom[i] + b[f]  (in place; becomes next layer input)
__global__ __launch_bounds__(256) void finalize_kernel(
    float* __restrict__ acc, const float* __restrict__ denom,
    const float* __restrict__ b, int N)
{
    int t = blockIdx.x * blockDim.x + threadIdx.x;
    if (t >= N * HDIM) return;
    int i = t >> 5, f = t & 31;
    acc[t] = acc[t] / denom[i] + b[f];
}

__global__ __launch_bounds__(256) void pool_kernel(
    const float* __restrict__ x, const int* __restrict__ batch,
    float* __restrict__ psum, float* __restrict__ pcnt, int N)
{
    int t = blockIdx.x * blockDim.x + threadIdx.x;
    int lane = t & 31, i = t >> 5;
    if (i >= N) return;
    int g = batch[i];
    atomicAdd(&psum[(size_t)g * HDIM + lane], x[(size_t)i * HDIM + lane]);
    if (lane == 0) atomicAdd(&pcnt[g], 1.f);
}

__global__ __launch_bounds__(256) void pool_div(
    const float* __restrict__ psum, const float* __restrict__ pcnt,
    float* __restrict__ out, int G)
{
    int t = blockIdx.x * blockDim.x + threadIdx.x;
    if (t >= G * HDIM) return;
    int g = t >> 5;
    out[t] = psum[t] / fmaxf(pcnt[g], 1.f);
}

extern "C" void kernel_launch(void* const* d_in, const int* in_sizes, int n_in,
                              void* d_out, int out_size, void* d_ws, size_t ws_size,
                              hipStream_t stream) {
    const float* x          = (const float*)d_in[0];
    const int*   edge_index = (const int*)d_in[1];
    const int*   batch      = (const int*)d_in[2];

    const int N    = in_sizes[2];          // 100000
    const int E    = in_sizes[1] / 2;      // 1600000
    const int G    = out_size / HDIM;      // 2048
    const int Etot = E + N;                // self-loops appended

    const int* srcs = edge_index;          // edge_index[0]
    const int* dsts = edge_index + E;      // edge_index[1]

    float* ws    = (float*)d_ws;
    float* h     = ws;                         // N*H
    float* acc   = h + (size_t)N * HDIM;       // N*H (in-place layer output)
    float* es    = acc + (size_t)N * HDIM;     // N
    float* ed    = es + N;                     // N
    float* denom = ed + N;                     // N
    float* psum  = denom + N;                  // G*H
    float* pcnt  = psum + (size_t)G * HDIM;    // G

    const float* xin = x;
    for (int l = 0; l < 4; l++) {
        const float* W   = (const float*)d_in[3 + 4 * l];
        const float* a_s = (const float*)d_in[4 + 4 * l];
        const float* a_d = (const float*)d_in[5 + 4 * l];
        const float* b   = (const float*)d_in[6 + 4 * l];

        if (l == 0) gemm128<<<2048, 256, 0, stream>>>(xin, W, a_s, a_d, h, es, ed, N);
        else        gemm32 <<<2048, 256, 0, stream>>>(xin, W, a_s, a_d, h, es, ed, N);

        hipMemsetAsync(acc,   0, (size_t)N * HDIM * sizeof(float), stream);
        hipMemsetAsync(denom, 0, (size_t)N * sizeof(float), stream);

        int nthreads = Etot * 32;
        edge_kernel<<<(nthreads + 255) / 256, 256, 0, stream>>>(h, es, ed, srcs, dsts, E, Etot, acc, denom);
        finalize_kernel<<<(N * HDIM + 255) / 256, 256, 0, stream>>>(acc, denom, b, N);
        xin = acc;
    }

    hipMemsetAsync(psum, 0, (size_t)(G * HDIM + G) * sizeof(float), stream);
    pool_kernel<<<(N * 32 + 255) / 256, 256, 0, stream>>>(acc, batch, psum, pcnt, N);
    pool_div<<<(G * HDIM + 255) / 256, 256, 0, stream>>>(psum, pcnt, (float*)d_out, G);
}

// Round 2
// 911.559 us; speedup vs baseline: 1.5107x; 1.5107x over previous
//
#include <hip/hip_runtime.h>

#define HDIM 32
#define IN_DIM 128
#define NEG_SLOPE 0.2f
#define SCAN_BS 256

__device__ __forceinline__ float leaky(float e) {
    return (e >= 0.f) ? e : NEG_SLOPE * e;
}

// ---------------- GEMM kernels (unchanged structure) ----------------

__global__ __launch_bounds__(256) void gemm128(
    const float* __restrict__ x, const float* __restrict__ W,
    const float* __restrict__ a_s, const float* __restrict__ a_d,
    float* __restrict__ h, float* __restrict__ es, float* __restrict__ ed, int N)
{
    __shared__ float Ws[IN_DIM * HDIM];
    __shared__ float xs[8][IN_DIM];
    const int tid = threadIdx.x;
    for (int i = tid; i < IN_DIM * HDIM; i += 256) Ws[i] = W[i];
    const int col = tid & 31;
    const int rl  = tid >> 5;
    const float as_c = a_s[col], ad_c = a_d[col];
    for (int tile = blockIdx.x; tile * 8 < N; tile += gridDim.x) {
        const int row0 = tile * 8;
        __syncthreads();
        for (int i = tid; i < 8 * IN_DIM; i += 256) {
            int r = i >> 7, c = i & 127;
            int gr = row0 + r;
            xs[r][c] = (gr < N) ? x[(size_t)gr * IN_DIM + c] : 0.f;
        }
        __syncthreads();
        const int row = row0 + rl;
        float acc = 0.f;
        #pragma unroll 8
        for (int k = 0; k < IN_DIM; k++) acc += xs[rl][k] * Ws[k * HDIM + col];
        float ps = acc * as_c, pd = acc * ad_c;
        #pragma unroll
        for (int m = 16; m >= 1; m >>= 1) { ps += __shfl_xor(ps, m); pd += __shfl_xor(pd, m); }
        if (row < N) {
            h[(size_t)row * HDIM + col] = acc;
            if (col == 0) { es[row] = ps; ed[row] = pd; }
        }
    }
}

__global__ __launch_bounds__(256) void gemm32(
    const float* __restrict__ x, const float* __restrict__ W,
    const float* __restrict__ a_s, const float* __restrict__ a_d,
    float* __restrict__ h, float* __restrict__ es, float* __restrict__ ed, int N)
{
    __shared__ float Ws[HDIM * HDIM];
    __shared__ float xs[8][HDIM];
    const int tid = threadIdx.x;
    for (int i = tid; i < HDIM * HDIM; i += 256) Ws[i] = W[i];
    const int col = tid & 31;
    const int rl  = tid >> 5;
    const float as_c = a_s[col], ad_c = a_d[col];
    for (int tile = blockIdx.x; tile * 8 < N; tile += gridDim.x) {
        const int row0 = tile * 8;
        __syncthreads();
        {
            int r = tid >> 5, c = tid & 31;
            int gr = row0 + r;
            xs[r][c] = (gr < N) ? x[(size_t)gr * HDIM + c] : 0.f;
        }
        __syncthreads();
        const int row = row0 + rl;
        float acc = 0.f;
        #pragma unroll
        for (int k = 0; k < HDIM; k++) acc += xs[rl][k] * Ws[k * HDIM + col];
        float ps = acc * as_c, pd = acc * ad_c;
        #pragma unroll
        for (int m = 16; m >= 1; m >>= 1) { ps += __shfl_xor(ps, m); pd += __shfl_xor(pd, m); }
        if (row < N) {
            h[(size_t)row * HDIM + col] = acc;
            if (col == 0) { es[row] = ps; ed[row] = pd; }
        }
    }
}

// ---------------- CSR build (once per call; edge set shared by all layers) --

__global__ __launch_bounds__(256) void hist_kernel(
    const int* __restrict__ dsts, int E, int* __restrict__ deg)
{
    int e = blockIdx.x * blockDim.x + threadIdx.x;
    if (e < E) atomicAdd(&deg[dsts[e]], 1);
}

// per-block sums of deg
__global__ __launch_bounds__(SCAN_BS) void scan_reduce(
    const int* __restrict__ deg, int N, int* __restrict__ bsums)
{
    __shared__ int sdata[SCAN_BS];
    int i = blockIdx.x * SCAN_BS + threadIdx.x;
    int v = (i < N) ? deg[i] : 0;
    sdata[threadIdx.x] = v;
    __syncthreads();
    for (int off = SCAN_BS >> 1; off > 0; off >>= 1) {
        if (threadIdx.x < off) sdata[threadIdx.x] += sdata[threadIdx.x + off];
        __syncthreads();
    }
    if (threadIdx.x == 0) bsums[blockIdx.x] = sdata[0];
}

// exclusive scan of block sums (nb ~ 391, trivial sequential)
__global__ void scan_top(int* __restrict__ bsums, int nb)
{
    if (threadIdx.x == 0 && blockIdx.x == 0) {
        int run = 0;
        for (int i = 0; i < nb; i++) { int t = bsums[i]; bsums[i] = run; run += t; }
    }
}

// per-block exclusive scan + offset -> rowptr, cursor
__global__ __launch_bounds__(SCAN_BS) void scan_final(
    const int* __restrict__ deg, int N, const int* __restrict__ bsums,
    int* __restrict__ rowptr, int* __restrict__ cursor)
{
    __shared__ int sdata[SCAN_BS];
    int i = blockIdx.x * SCAN_BS + threadIdx.x;
    int t = threadIdx.x;
    int v = (i < N) ? deg[i] : 0;
    sdata[t] = v;
    __syncthreads();
    for (int off = 1; off < SCAN_BS; off <<= 1) {
        int add = (t >= off) ? sdata[t - off] : 0;
        __syncthreads();
        sdata[t] += add;
        __syncthreads();
    }
    if (i < N) {
        int excl = sdata[t] - v + bsums[blockIdx.x];
        rowptr[i] = excl;
        cursor[i] = excl;
    }
}

__global__ __launch_bounds__(256) void scatter_kernel(
    const int* __restrict__ srcs, const int* __restrict__ dsts, int E,
    int* __restrict__ cursor, int* __restrict__ csrsrc)
{
    int e = blockIdx.x * blockDim.x + threadIdx.x;
    if (e >= E) return;
    int d = dsts[e];
    int idx = atomicAdd(&cursor[d], 1);
    csrsrc[idx] = srcs[e];
}

// ---------------- Gather aggregation: one 32-lane group per node ----------

__global__ __launch_bounds__(256) void agg_kernel(
    const float* __restrict__ h, const float* __restrict__ es, const float* __restrict__ ed,
    const int* __restrict__ rowptr, const int* __restrict__ deg,
    const int* __restrict__ csrsrc, const float* __restrict__ b,
    float* __restrict__ out, int N)
{
    int lane = threadIdx.x & 31;
    int node = blockIdx.x * 8 + (threadIdx.x >> 5);
    if (node >= N) return;

    const int base = rowptr[node];
    const int degi = deg[node];
    const float edi = ed[node];

    float accf = 0.f, den = 0.f;

    int s_cur = (degi > 0) ? csrsrc[base] : 0;
    for (int k = 0; k < degi; k++) {
        int s_nxt = (k + 1 < degi) ? csrsrc[base + k + 1] : 0;
        float w = __expf(leaky(es[s_cur] + edi));
        accf += w * h[(size_t)s_cur * HDIM + lane];
        den  += w;
        s_cur = s_nxt;
    }
    // self-loop (reference appends one per node)
    {
        float w = __expf(leaky(es[node] + edi));
        accf += w * h[(size_t)node * HDIM + lane];
        den  += w;
    }
    out[(size_t)node * HDIM + lane] = accf / den + b[lane];
}

// ---------------- Pool ----------------

__global__ __launch_bounds__(256) void pool_kernel(
    const float* __restrict__ x, const int* __restrict__ batch,
    float* __restrict__ psum, float* __restrict__ pcnt, int N)
{
    int t = blockIdx.x * blockDim.x + threadIdx.x;
    int lane = t & 31, i = t >> 5;
    if (i >= N) return;
    int g = batch[i];
    atomicAdd(&psum[(size_t)g * HDIM + lane], x[(size_t)i * HDIM + lane]);
    if (lane == 0) atomicAdd(&pcnt[g], 1.f);
}

__global__ __launch_bounds__(256) void pool_div(
    const float* __restrict__ psum, const float* __restrict__ pcnt,
    float* __restrict__ out, int G)
{
    int t = blockIdx.x * blockDim.x + threadIdx.x;
    if (t >= G * HDIM) return;
    int g = t >> 5;
    out[t] = psum[t] / fmaxf(pcnt[g], 1.f);
}

// ---------------- Launch ----------------

extern "C" void kernel_launch(void* const* d_in, const int* in_sizes, int n_in,
                              void* d_out, int out_size, void* d_ws, size_t ws_size,
                              hipStream_t stream) {
    const float* x          = (const float*)d_in[0];
    const int*   edge_index = (const int*)d_in[1];
    const int*   batch      = (const int*)d_in[2];

    const int N = in_sizes[2];          // 100000
    const int E = in_sizes[1] / 2;      // 1600000
    const int G = out_size / HDIM;      // 2048

    const int* srcs = edge_index;
    const int* dsts = edge_index + E;

    const int nb = (N + SCAN_BS - 1) / SCAN_BS;

    // workspace layout
    char* p = (char*)d_ws;
    float* h      = (float*)p; p += (size_t)N * HDIM * sizeof(float);
    float* xbuf   = (float*)p; p += (size_t)N * HDIM * sizeof(float);
    float* es     = (float*)p; p += (size_t)N * sizeof(float);
    float* ed     = (float*)p; p += (size_t)N * sizeof(float);
    int*   deg    = (int*)p;   p += (size_t)N * sizeof(int);
    int*   rowptr = (int*)p;   p += (size_t)N * sizeof(int);
    int*   cursor = (int*)p;   p += (size_t)N * sizeof(int);
    int*   csrsrc = (int*)p;   p += (size_t)E * sizeof(int);
    int*   bsums  = (int*)p;   p += (size_t)nb * sizeof(int);
    float* psum   = (float*)p; p += (size_t)G * HDIM * sizeof(float);
    float* pcnt   = (float*)p; p += (size_t)G * sizeof(float);

    // ---- CSR build (once; same edge set for all 4 layers) ----
    hipMemsetAsync(deg, 0, (size_t)N * sizeof(int), stream);
    hist_kernel<<<(E + 255) / 256, 256, 0, stream>>>(dsts, E, deg);
    scan_reduce<<<nb, SCAN_BS, 0, stream>>>(deg, N, bsums);
    scan_top<<<1, 64, 0, stream>>>(bsums, nb);
    scan_final<<<nb, SCAN_BS, 0, stream>>>(deg, N, bsums, rowptr, cursor);
    scatter_kernel<<<(E + 255) / 256, 256, 0, stream>>>(srcs, dsts, E, cursor, csrsrc);

    // ---- 4 GAT layers ----
    const float* xin = x;
    for (int l = 0; l < 4; l++) {
        const float* W   = (const float*)d_in[3 + 4 * l];
        const float* a_s = (const float*)d_in[4 + 4 * l];
        const float* a_d = (const float*)d_in[5 + 4 * l];
        const float* b   = (const float*)d_in[6 + 4 * l];

        if (l == 0) gemm128<<<2048, 256, 0, stream>>>(xin, W, a_s, a_d, h, es, ed, N);
        else        gemm32 <<<2048, 256, 0, stream>>>(xin, W, a_s, a_d, h, es, ed, N);

        agg_kernel<<<(N + 7) / 8, 256, 0, stream>>>(h, es, ed, rowptr, deg, csrsrc, b, xbuf, N);
        xin = xbuf;
    }

    // ---- global mean pool ----
    hipMemsetAsync(psum, 0, (size_t)(G * HDIM + G) * sizeof(float), stream);
    pool_kernel<<<(N * 32 + 255) / 256, 256, 0, stream>>>(xbuf, batch, psum, pcnt, N);
    pool_div<<<(G * HDIM + 255) / 256, 256, 0, stream>>>(psum, pcnt, (float*)d_out, G);
}